// Round 1
// baseline (1055.682 us; speedup 1.0000x reference)
//
#include <hip/hip_runtime.h>
#include <stdint.h>

typedef _Float16 f16;
typedef _Float16 f16x8 __attribute__((ext_vector_type(8)));
typedef float f32x4 __attribute__((ext_vector_type(4)));

#define NROWS 16384
#define DIM   512
#define NEXP  8
#define BM    128
#define BN    128
#define BK    32
#define KSTEPS (DIM/BK)

// async global->LDS, 16B per lane, LDS dest = wave-uniform base + lane*16
#define GLOAD16(gp, lp) __builtin_amdgcn_global_load_lds( \
    (const __attribute__((address_space(1))) void*)(gp),  \
    (__attribute__((address_space(3))) void*)(lp), 16, 0, 0)

// ---------- prep: W[l][e][i][o] fp32 -> Wt[l][e][o][i] fp16 (transpose+convert) ----------
__global__ __launch_bounds__(256) void convert_w(
    const float* __restrict__ w0, const float* __restrict__ w1,
    const float* __restrict__ w2, const float* __restrict__ wo,
    f16* __restrict__ Wt)
{
    __shared__ float tile[32][33];
    int b  = blockIdx.x;            // m*256 + bi*16 + bj
    int m  = b >> 8;                // 0..31  (layer*8 + expert)
    int bi = (b >> 4) & 15;
    int bj = b & 15;
    int layer = m >> 3;
    const float* src =
        (layer == 0 ? w0 : layer == 1 ? w1 : layer == 2 ? w2 : wo)
        + (size_t)(m & 7) * DIM * DIM;
    f16* dst = Wt + (size_t)m * DIM * DIM;
    int tx = threadIdx.x & 31, ty = threadIdx.x >> 5;
#pragma unroll
    for (int r = 0; r < 4; ++r)
        tile[ty + 8*r][tx] = src[(size_t)(bi*32 + ty + 8*r) * DIM + bj*32 + tx];
    __syncthreads();
#pragma unroll
    for (int r = 0; r < 4; ++r)
        dst[(size_t)(bj*32 + ty + 8*r) * DIM + bi*32 + tx] = (f16)tile[tx][ty + 8*r];
}

// ---------- prep: alpha = softmax(x@gate_w + gate_b); xh = fp16(x) ----------
__global__ __launch_bounds__(256) void gate_kernel(
    const float* __restrict__ x, const float* __restrict__ gw,
    const float* __restrict__ gb, float* __restrict__ alpha,
    f16* __restrict__ xh)
{
    int tid = threadIdx.x, lane = tid & 63, wid = tid >> 6;
    int row = blockIdx.x * 4 + wid;           // one row per wave
    const float* xr = x + (size_t)row * DIM;
    float acc[8] = {0,0,0,0,0,0,0,0};
    float xv[8];
#pragma unroll
    for (int j = 0; j < 8; ++j) {
        int d = lane + 64*j;
        float v = xr[d];
        xv[j] = v;
        const float4* g = (const float4*)(gw + (size_t)d * 8);
        float4 g0 = g[0], g1 = g[1];
        acc[0] += v*g0.x; acc[1] += v*g0.y; acc[2] += v*g0.z; acc[3] += v*g0.w;
        acc[4] += v*g1.x; acc[5] += v*g1.y; acc[6] += v*g1.z; acc[7] += v*g1.w;
    }
#pragma unroll
    for (int mlane = 32; mlane >= 1; mlane >>= 1) {
#pragma unroll
        for (int k = 0; k < 8; ++k) acc[k] += __shfl_xor(acc[k], mlane, 64);
    }
#pragma unroll
    for (int k = 0; k < 8; ++k) acc[k] += gb[k];
    float mx = acc[0];
#pragma unroll
    for (int k = 1; k < 8; ++k) mx = fmaxf(mx, acc[k]);
    float s = 0.f;
#pragma unroll
    for (int k = 0; k < 8; ++k) { acc[k] = __expf(acc[k] - mx); s += acc[k]; }
    float inv = 1.0f / s;
    if (lane == 0) {
        float4 a0 = {acc[0]*inv, acc[1]*inv, acc[2]*inv, acc[3]*inv};
        float4 a1 = {acc[4]*inv, acc[5]*inv, acc[6]*inv, acc[7]*inv};
        *(float4*)(alpha + (size_t)row*8)     = a0;
        *(float4*)(alpha + (size_t)row*8 + 4) = a1;
    }
#pragma unroll
    for (int j = 0; j < 8; ++j)
        xh[(size_t)row * DIM + lane + 64*j] = (f16)xv[j];
}

// ---------- main fused MoIE layer: out = [relu]( sum_e alpha_e * (A @ W_e) + alpha.bias ) ----------
template<int RELU, int OUTF32>
__global__ __launch_bounds__(256, 2) void moie_gemm(
    const f16*  __restrict__ A,      // [16384][512] fp16
    const f16*  __restrict__ Wt,     // [8][512 o][512 i] fp16 (this layer, o-major)
    const float* __restrict__ alpha, // [16384][8]
    const float* __restrict__ bias,  // [8][512]
    f16*  __restrict__ Hout,         // fp16 out (RELU path)
    float* __restrict__ Fout)        // fp32 out (final layer)
{
    __shared__ __align__(16) f16 As[BM*BK];   // [row][k], 64B rows, granule-swizzled
    __shared__ __align__(16) f16 Bs[BN*BK];   // [col][k], same swizzle
    __shared__ float alpha_s[BM*9];           // stride 9 to break bank aliasing
    __shared__ float bias_s[NEXP*BN];

    int bid = blockIdx.x;
    int cb = bid >> 7, rb = bid & 127;        // cb-major grid: same-row blocks co-XCD
    int rowBase = rb * BM, colBase = cb * BN;
    int tid = threadIdx.x, lane = tid & 63, wid = tid >> 6;
    int wm = wid >> 1, wn = wid & 1;

    for (int i = tid; i < BM*NEXP; i += 256)
        alpha_s[(i >> 3)*9 + (i & 7)] = alpha[(size_t)(rowBase + (i >> 3))*8 + (i & 7)];
    for (int i = tid; i < NEXP*BN; i += 256)
        bias_s[i] = bias[(i >> 7)*DIM + colBase + (i & 127)];

    // staging: wave wid owns 1KB chunks {2wid, 2wid+1} of each 8KB tile.
    // lane i -> LDS row = chunk*16 + (i>>2), granule (i&3). XOR swizzle: slot (r,g)
    // holds global k-granule g^(r&3)  (source-side swizzle, read-side matches).
    int sg = ((lane & 3) ^ ((lane >> 2) & 3)) * 8;   // swizzled source k-offset (elems)
    const f16* aSrc0 = A + (size_t)(rowBase + wid*32 + (lane >> 2)) * DIM + sg;
    const f16* aSrc1 = aSrc0 + (size_t)16 * DIM;
    const f16* bSrcBase = Wt + (size_t)(colBase + wid*32 + (lane >> 2)) * DIM + sg;
    f16* aDst0 = As + wid*1024;   // 2wid*1024 bytes
    f16* aDst1 = As + wid*1024 + 512;
    f16* bDst0 = Bs + wid*1024;
    f16* bDst1 = Bs + wid*1024 + 512;

    // fragment read offsets (elems): row = *64?no -> (lane&15); k-granule = (lane>>4)^(row&3)
    int kg  = ((lane >> 4) ^ (lane & 3)) * 8;
    int aOff = (wm*64 + (lane & 15)) * BK + kg;
    int bOff = (wn*64 + (lane & 15)) * BK + kg;

    f32x4 accT[4][4];
#pragma unroll
    for (int i = 0; i < 4; ++i)
#pragma unroll
        for (int j = 0; j < 4; ++j) accT[i][j] = (f32x4){0.f,0.f,0.f,0.f};

    for (int e = 0; e < NEXP; ++e) {
        f32x4 accE[4][4];
#pragma unroll
        for (int i = 0; i < 4; ++i)
#pragma unroll
            for (int j = 0; j < 4; ++j) accE[i][j] = (f32x4){0.f,0.f,0.f,0.f};
        const f16* bSrc = bSrcBase + (size_t)e * DIM * DIM;

        for (int ks = 0; ks < KSTEPS; ++ks) {
            __syncthreads();   // previous step's LDS reads done before overwrite
            GLOAD16(aSrc0 + ks*BK, aDst0);
            GLOAD16(aSrc1 + ks*BK, aDst1);
            GLOAD16(bSrc  + ks*BK, bDst0);
            GLOAD16(bSrc + 16*DIM + ks*BK, bDst1);
            __syncthreads();   // compiler drains vmcnt before barrier -> tile ready

            f16x8 af[4], bf[4];
#pragma unroll
            for (int i = 0; i < 4; ++i) af[i] = *(const f16x8*)(As + aOff + i*512);
#pragma unroll
            for (int i = 0; i < 4; ++i) bf[i] = *(const f16x8*)(Bs + bOff + i*512);
#pragma unroll
            for (int i = 0; i < 4; ++i)
#pragma unroll
                for (int j = 0; j < 4; ++j)
                    accE[i][j] = __builtin_amdgcn_mfma_f32_16x16x32_f16(
                        af[i], bf[j], accE[i][j], 0, 0, 0);
        }
        // expert boundary: accT += alpha[row, e] * accE   (fp32, exact blend)
#pragma unroll
        for (int i = 0; i < 4; ++i)
#pragma unroll
            for (int q = 0; q < 4; ++q) {
                float al = alpha_s[(wm*64 + i*16 + (lane >> 4)*4 + q)*9 + e];
#pragma unroll
                for (int j = 0; j < 4; ++j)
                    accT[i][j][q] += al * accE[i][j][q];
            }
    }

    // epilogue: + sum_e alpha*bias, relu, store
#pragma unroll
    for (int i = 0; i < 4; ++i)
#pragma unroll
        for (int q = 0; q < 4; ++q) {
            int rloc = wm*64 + i*16 + (lane >> 4)*4 + q;
            size_t row = (size_t)(rowBase + rloc);
#pragma unroll
            for (int j = 0; j < 4; ++j) {
                int cloc = wn*64 + j*16 + (lane & 15);
                float v = accT[i][j][q];
#pragma unroll
                for (int e2 = 0; e2 < NEXP; ++e2)
                    v += alpha_s[rloc*9 + e2] * bias_s[e2*BN + cloc];
                if (RELU) v = fmaxf(v, 0.f);
                if (OUTF32) Fout[row*DIM + colBase + cloc] = v;
                else        Hout[row*DIM + colBase + cloc] = (f16)v;
            }
        }
}

extern "C" void kernel_launch(void* const* d_in, const int* in_sizes, int n_in,
                              void* d_out, int out_size, void* d_ws, size_t ws_size,
                              hipStream_t stream)
{
    const float* x  = (const float*)d_in[0];
    const float* gw = (const float*)d_in[1];
    const float* gb = (const float*)d_in[2];
    const float* w0 = (const float*)d_in[3];
    const float* b0 = (const float*)d_in[4];
    const float* w1 = (const float*)d_in[5];
    const float* b1 = (const float*)d_in[6];
    const float* w2 = (const float*)d_in[7];
    const float* b2 = (const float*)d_in[8];
    const float* wo = (const float*)d_in[9];
    const float* bo = (const float*)d_in[10];
    float* out = (float*)d_out;

    // workspace layout: Wt (16MB) | alpha (512KB) | h0 (16MB) | h1 (16MB)  = ~49MB
    char* ws = (char*)d_ws;
    const size_t wtBytes = (size_t)4 * NEXP * DIM * DIM * sizeof(f16);
    f16*   Wt    = (f16*)ws;
    float* alpha = (float*)(ws + wtBytes);
    f16*   h0    = (f16*)(ws + wtBytes + (size_t)NROWS*NEXP*sizeof(float));
    f16*   h1    = h0 + (size_t)NROWS * DIM;
    const size_t L = (size_t)NEXP * DIM * DIM;   // elems per layer of Wt

    convert_w<<<8192, 256, 0, stream>>>(w0, w1, w2, wo, Wt);
    gate_kernel<<<NROWS/4, 256, 0, stream>>>(x, gw, gb, alpha, h0);

    moie_gemm<1,0><<<512, 256, 0, stream>>>(h0, Wt,       alpha, b0, h1, nullptr);
    moie_gemm<1,0><<<512, 256, 0, stream>>>(h1, Wt + L,   alpha, b1, h0, nullptr);
    moie_gemm<1,0><<<512, 256, 0, stream>>>(h0, Wt + 2*L, alpha, b2, h1, nullptr);
    moie_gemm<0,1><<<512, 256, 0, stream>>>(h1, Wt + 3*L, alpha, bo, nullptr, out);
}